// Round 14
// baseline (466.171 us; speedup 1.0000x reference)
//
#include <hip/hip_runtime.h>
#include <stdint.h>
#include <stddef.h>

#define MROWS 32768
#define HDIM  512
#define CH    16384
#define BM 128
#define BN 128
#define BK 64

typedef __attribute__((ext_vector_type(8))) _Float16 half8;
typedef __attribute__((ext_vector_type(4))) _Float16 half4v;
typedef __attribute__((ext_vector_type(4))) float    f32x4;

// global -> LDS direct (16B/lane). LDS dest = wave-uniform base + lane*16.
static __device__ __forceinline__ void gld_lds16(const void* g, void* l) {
    __builtin_amdgcn_global_load_lds(
        (__attribute__((address_space(1))) void*)(uintptr_t)g,
        (__attribute__((address_space(3))) void*)(uint32_t)(uintptr_t)l,
        16, 0, 0);
}

// ---------------- fp32 -> fp16 row-structured conversion (weights) ------------
struct CvtJob  { const float* src; _Float16* dst; int srcld4, dstld, rowlen4, rows; };
struct CvtJobs { CvtJob j[11]; };

__global__ __launch_bounds__(256)
void cvt_rows(CvtJobs J) {
    const CvtJob jb = J.j[blockIdx.y];
    const int row = blockIdx.x;
    if (row >= jb.rows) return;
    const float4* __restrict__ s = (const float4*)jb.src + (size_t)row * jb.srcld4;
    _Float16* __restrict__ d = jb.dst + (size_t)row * jb.dstld;
    for (int c = threadIdx.x; c < jb.rowlen4; c += 256) {
        const float4 v = s[c];
        half4v o = { (_Float16)v.x, (_Float16)v.y, (_Float16)v.z, (_Float16)v.w };
        *(half4v*)(d + c * 4) = o;
    }
}

// ---------------- fp32 X chunk -> packed fp16 strip [X0|X1|X2] (ld 1536) ------
__global__ __launch_bounds__(384)
void cvt_chunk3(const float* __restrict__ x0, const float* __restrict__ x1,
                const float* __restrict__ x2, _Float16* __restrict__ dst) {
    const int row = blockIdx.x;
    const int mod = threadIdx.x >> 7;      // 0..2 (wave-uniform)
    const int c   = threadIdx.x & 127;     // float4 index within row
    const float* s = (mod == 0) ? x0 : (mod == 1) ? x1 : x2;
    const float4 v = ((const float4*)(s + (size_t)row * 512))[c];
    half4v o = { (_Float16)v.x, (_Float16)v.y, (_Float16)v.z, (_Float16)v.w };
    *(half4v*)(dst + (size_t)row * 1536 + mod * 512 + c * 4) = o;
}

// ---------------- fp32 -> fp16 transpose (512x512): dst[k][i] = src[i][k] -----
struct TcvtArgs { const float* src[3]; _Float16* dst; };
__global__ __launch_bounds__(256)
void tcvt512(TcvtArgs a) {
    __shared__ float t[32][33];
    const int m = blockIdx.z;
    const float* __restrict__ src = a.src[m];
    _Float16* __restrict__ dst = a.dst + (size_t)m * HDIM * HDIM;
    const int bx = blockIdx.x * 32, by = blockIdx.y * 32;
    const int tx = threadIdx.x & 31, ty = threadIdx.x >> 5;  // ty 0..7
    #pragma unroll
    for (int q = 0; q < 4; ++q)
        t[ty + q * 8][tx] = src[(size_t)(by + ty + q * 8) * 512 + bx + tx];
    __syncthreads();
    #pragma unroll
    for (int q = 0; q < 4; ++q)
        dst[(size_t)(bx + ty + q * 8) * 512 + by + tx] = (_Float16)t[tx][ty + q * 8];
}

// ---------------- small matvec ------------------------------------------------
struct MvArgs { const float* W[3]; const float* x[3]; const float* b[3]; float* y; int ldw, woff; };
__global__ __launch_bounds__(256)
void mv3(MvArgs a) {
    const int m = blockIdx.y;
    const int i = blockIdx.x * 256 + threadIdx.x;
    const float* __restrict__ W = a.W[m] + (size_t)i * a.ldw + a.woff;
    const float* __restrict__ x = a.x[m];
    float s = a.b[m][i];
    for (int j = 0; j < 512; ++j) s += W[j] * x[j];
    a.y[m * 512 + i] = s;
}

// ---------------- 1-phase GEMM (prep / gate2 / fc2), proven r9-r13 ------------
struct GemmP {
    const void* A1;
    const _Float16* W; const float* bias; void* C;
    int K, ldA1, ldw, ldc, coff;
    int zsA, zsW, zsC;
};

template<int EPI, int OCC>
__global__ __launch_bounds__(256, OCC)
void gemm_k(GemmP p) {
    __shared__ __align__(16) unsigned char smem[32768];
    _Float16* Asm = (_Float16*)smem;
    _Float16* Bsm = (_Float16*)(smem + 16384);

    const int tid  = threadIdx.x;
    const int wid  = tid >> 6;
    const int lane = tid & 63;
    const int m0 = blockIdx.x * BM;
    const int n0 = blockIdx.y * BN;
    const ptrdiff_t zz = (ptrdiff_t)blockIdx.z;
    const _Float16* __restrict__ A1h = (const _Float16*)((const char*)p.A1 + zz * p.zsA);
    const _Float16* __restrict__ Wp  = (const _Float16*)((const char*)p.W + zz * p.zsW);
    char* Cz = (char*)p.C + zz * p.zsC;

    const int wr = (wid >> 1) * 64;
    const int wc = (wid & 1) * 64;
    const int l15 = lane & 15;
    const int lhi = lane >> 4;

    f32x4 acc[4][4] = {};

    for (int kt = 0; kt < p.K; kt += BK) {
        #pragma unroll
        for (int i = 0; i < 4; ++i) {
            const int seg = wid * 256 + i * 64 + lane;
            const int row = seg >> 3;
            const int ke  = (seg & 7) * 8;
            gld_lds16(Wp  + (size_t)(n0 + row) * p.ldw  + kt + ke, &Bsm[seg * 8]);
            gld_lds16(A1h + (size_t)(m0 + row) * p.ldA1 + kt + ke, &Asm[seg * 8]);
        }
        __syncthreads();
        #pragma unroll
        for (int kk = 0; kk < BK; kk += 32) {
            half8 fa[4], fb[4];
            #pragma unroll
            for (int i = 0; i < 4; ++i) {
                fa[i] = *(const half8*)&Asm[(wr + i * 16 + l15) * BK + kk + lhi * 8];
                fb[i] = *(const half8*)&Bsm[(wc + i * 16 + l15) * BK + kk + lhi * 8];
            }
            #pragma unroll
            for (int i = 0; i < 4; ++i)
                #pragma unroll
                for (int j = 0; j < 4; ++j)
                    acc[i][j] = __builtin_amdgcn_mfma_f32_16x16x32_f16(fa[i], fb[j], acc[i][j], 0, 0, 0);
        }
        __syncthreads();
    }

    if (EPI == 3) {
        float* Cf = (float*)smem;
        float* __restrict__ C = (float*)Cz;
        #pragma unroll
        for (int h = 0; h < 2; ++h) {
            if ((wr >> 6) == h) {
                #pragma unroll
                for (int j = 0; j < 4; ++j) {
                    const int col = wc + j * 16 + l15;
                    const float bia = p.bias ? p.bias[n0 + col] : 0.f;
                    #pragma unroll
                    for (int i = 0; i < 4; ++i)
                        #pragma unroll
                        for (int r = 0; r < 4; ++r)
                            Cf[(i * 16 + lhi * 4 + r) * 128 + col] = acc[i][j][r] + bia;
                }
            }
            __syncthreads();
            #pragma unroll
            for (int pph = 0; pph < 8; ++pph) {
                const int seg = pph * 256 + tid;
                const int row = seg >> 5, cs = seg & 31;
                const float4 v = *(const float4*)&Cf[row * 128 + cs * 4];
                *(float4*)&C[(size_t)(m0 + h * 64 + row) * p.ldc + n0 + cs * 4] = v;
            }
            __syncthreads();
        }
    } else {
        _Float16* Ct = (_Float16*)smem;
        #pragma unroll
        for (int j = 0; j < 4; ++j) {
            const int col = wc + j * 16 + l15;
            const float bia = (EPI == 2) ? 0.f : (p.bias ? p.bias[n0 + col] : 0.f);
            #pragma unroll
            for (int i = 0; i < 4; ++i)
                #pragma unroll
                for (int r = 0; r < 4; ++r) {
                    float v = acc[i][j][r] + bia;
                    if (EPI == 1) v = 1.f / (1.f + __expf(-v));
                    Ct[(wr + i * 16 + lhi * 4 + r) * 128 + col] = (_Float16)v;
                }
        }
        __syncthreads();
        _Float16* __restrict__ C = (_Float16*)Cz;
        #pragma unroll
        for (int pph = 0; pph < 8; ++pph) {
            const int seg = pph * 256 + tid;
            const int row = seg >> 4, cs = seg & 15;
            half8 hv = *(const half8*)&Ct[row * 128 + cs * 8];
            const size_t cidx = (size_t)(m0 + row) * p.ldc + p.coff + n0 + cs * 8;
            if (EPI == 1) {
                const half8 xv = *(const half8*)(A1h + (size_t)(m0 + row) * p.ldA1
                                                 + n0 + cs * 8);
                hv = hv * xv;
            }
            if (EPI == 2) { const half8 old = *(const half8*)&C[cidx]; hv = hv + old; }
            *(half8*)&C[cidx] = hv;
        }
    }
}

// ---------------- 8-phase 256x256 GEMM with counted vmcnt (T2+T3+T4+T5) ------
// 512 thr = 8 waves (2M x 4N); per-wave out 128x64.
// LDS layout: per operand [2 buf][2 kh][256 rows][4 x 16B] (kh = 32 K-cols).
// Phase ph=(kh,g): kh=ph>>1 selects K-half, g=ph&1 selects mf-group (4 mf).
// Staging: kh1(t+1) issued at t ph0; kh0(t+2) issued at t ph2.
// Waits (counted, never 0 in steady state):
//   end ph1: vmcnt(8) drains kh1(t)   [issued t-1 ph0, 5 phases earlier]
//   end ph3: vmcnt(8) drains kh0(t+1) [issued t-1 ph2, 5 phases earlier]
// Region safety: each staged region's last reads finished >=1 barrier earlier;
// per-wave lgkmcnt(0) before MFMA + 1 end-barrier/phase gives cross-wave
// visibility. Accumulation order per acc element identical to r13 (kh0 then
// kh1 per tile) -> bit-identical output.
// Swizzle: slot = lhi ^ ((row>>1)&3) on read; source col kc = i ^ ((row>>1)&3)
// on stage (both-sides rule #21). Bank-balanced (each 4-bank group 8 lanes).
struct Gemm8P {
    const _Float16* A; const _Float16* W; const float* bias; _Float16* C;
    int K, ldA, ldW, ldc, coff;
};

template<int EPI>
__global__ __launch_bounds__(512, 1)
void gemm8(Gemm8P p) {
    __shared__ __align__(16) unsigned char lds[131072];
    char* LA = (char*)lds;             // A regions: (q*2+kh)*16KB
    char* LB = (char*)lds + 65536;

    const int tid  = threadIdx.x;
    const int wid  = tid >> 6;
    const int lane = tid & 63;
    const int wm = wid >> 2;           // 0..1
    const int wn = wid & 3;            // 0..3
    const int l15 = lane & 15;
    const int lhi = lane >> 4;
    const int m0 = blockIdx.x * 256;
    const int n0 = blockIdx.y * 256;
    const _Float16* __restrict__ A = p.A;
    const _Float16* __restrict__ W = p.W;
    const int ldA = p.ldA, ldW = p.ldW;
    const int nT = p.K >> 6;

    f32x4 acc[8][4] = {};

    auto stageh = [&](const _Float16* src, int ld, int r0, char* base, int t, int kh) {
        const int q = t & 1;
        const int kt = t * 64 + kh * 32;
        char* dst = base + (size_t)(q * 2 + kh) * 16384;
        #pragma unroll
        for (int k = 0; k < 2; ++k) {
            const int j = tid + k * 512;          // 0..1023
            const int row = j >> 2, i = j & 3;
            const int kc = i ^ ((row >> 1) & 3);  // pre-swizzled source col
            gld_lds16(src + (size_t)(r0 + row) * ld + kt + kc * 8,
                      dst + (size_t)j * 16);
        }
    };
    #define STAGE8(t, kh) { stageh(A, ldA, m0, LA, (t), (kh)); stageh(W, ldW, n0, LB, (t), (kh)); }

    // prologue: kh0(0), kh1(0), kh0(1) -> ages mimic steady state
    STAGE8(0, 0);
    STAGE8(0, 1);
    if (nT > 1) { STAGE8(1, 0); asm volatile("s_waitcnt vmcnt(8)" ::: "memory"); }
    else        {               asm volatile("s_waitcnt vmcnt(0)" ::: "memory"); }
    __builtin_amdgcn_s_barrier();
    asm volatile("" ::: "memory");

    for (int t = 0; t < nT; ++t) {
        const int q = t & 1;
        half8 fb[4];
        #pragma unroll
        for (int ph = 0; ph < 4; ++ph) {
            const int kh = ph >> 1, g = ph & 1;
            const char* ra = LA + (size_t)(q * 2 + kh) * 16384;
            const char* rb = LB + (size_t)(q * 2 + kh) * 16384;
            half8 fa[4];
            if (g == 0) {
                #pragma unroll
                for (int nf = 0; nf < 4; ++nf) {
                    const int row = wn * 64 + nf * 16 + l15;
                    const int sl = lhi ^ ((row >> 1) & 3);
                    fb[nf] = *(const half8*)(rb + ((size_t)row * 4 + sl) * 16);
                }
            }
            #pragma unroll
            for (int mi = 0; mi < 4; ++mi) {
                const int row = wm * 128 + (g * 4 + mi) * 16 + l15;
                const int sl = lhi ^ ((row >> 1) & 3);
                fa[mi] = *(const half8*)(ra + ((size_t)row * 4 + sl) * 16);
            }
            if (ph == 0 && t + 1 < nT) STAGE8(t + 1, 1);
            if (ph == 2 && t + 2 < nT) STAGE8(t + 2, 0);
            asm volatile("s_waitcnt lgkmcnt(0)" ::: "memory");
            __builtin_amdgcn_sched_barrier(0);
            __builtin_amdgcn_s_setprio(1);
            #pragma unroll
            for (int mi = 0; mi < 4; ++mi)
                #pragma unroll
                for (int nf = 0; nf < 4; ++nf)
                    acc[g * 4 + mi][nf] = __builtin_amdgcn_mfma_f32_16x16x32_f16(
                        fa[mi], fb[nf], acc[g * 4 + mi][nf], 0, 0, 0);
            __builtin_amdgcn_s_setprio(0);
            if (ph == 1) {
                if (t + 1 < nT) asm volatile("s_waitcnt vmcnt(8)" ::: "memory");
                else            asm volatile("s_waitcnt vmcnt(0)" ::: "memory");
            }
            if (ph == 3) {
                if (t + 2 < nT)      asm volatile("s_waitcnt vmcnt(8)" ::: "memory");
                else if (t + 1 < nT) asm volatile("s_waitcnt vmcnt(4)" ::: "memory");
            }
            asm volatile("" ::: "memory");
            __builtin_amdgcn_s_barrier();
            asm volatile("" ::: "memory");
        }
    }

    // epilogue: fragments -> LDS (256x256 fp16 = 128KB, buffers dead) -> stores
    _Float16* Ct = (_Float16*)lds;
    #pragma unroll
    for (int mf = 0; mf < 8; ++mf)
        #pragma unroll
        for (int nf = 0; nf < 4; ++nf) {
            const int col = wn * 64 + nf * 16 + l15;
            const float bia = p.bias[n0 + col];
            #pragma unroll
            for (int r = 0; r < 4; ++r) {
                float v = acc[mf][nf][r] + bia;
                if (EPI == 1) v = 1.f / (1.f + __expf(-v));   // sigma
                Ct[(wm * 128 + mf * 16 + lhi * 4 + r) * 256 + col] = (_Float16)v;
            }
        }
    __syncthreads();
    #pragma unroll
    for (int it = 0; it < 16; ++it) {
        const int u = it * 512 + tid;          // 8192 x 16B units
        const int row = u >> 5, cs = u & 31;
        half8 hv = *(const half8*)&Ct[row * 256 + cs * 8];
        if (EPI == 1) {
            const half8 xv = *(const half8*)(A + (size_t)(m0 + row) * ldA + n0 + cs * 8);
            hv = hv * xv;                       // x * sigmoid
        }
        *(half8*)&p.C[(size_t)(m0 + row) * p.ldc + p.coff + n0 + cs * 8] = hv;
    }
}

// ---------------- LayerNorm(1024) + ReLU: d_out(h fp16) -> ws(h' fp16) --------
__global__ __launch_bounds__(256)
void ln_relu(const _Float16* __restrict__ hin, _Float16* __restrict__ hout,
             const float* __restrict__ gamma, const float* __restrict__ beta) {
    const int row  = blockIdx.x * 4 + (threadIdx.x >> 6);
    const int lane = threadIdx.x & 63;
    const _Float16* hr = hin + (size_t)row * 1024;
    _Float16* ho = hout + (size_t)row * 1024;
    const half8 v0 = *(const half8*)(hr + lane * 8);
    const half8 v1 = *(const half8*)(hr + 512 + lane * 8);
    float f0[8], f1[8];
    float s = 0.f, s2 = 0.f;
    #pragma unroll
    for (int j = 0; j < 8; ++j) {
        f0[j] = (float)v0[j]; s += f0[j]; s2 += f0[j] * f0[j];
        f1[j] = (float)v1[j]; s += f1[j]; s2 += f1[j] * f1[j];
    }
    #pragma unroll
    for (int off = 32; off > 0; off >>= 1) {
        s  += __shfl_xor(s,  off, 64);
        s2 += __shfl_xor(s2, off, 64);
    }
    const float mean = s * (1.f / 1024.f);
    const float var  = s2 * (1.f / 1024.f) - mean * mean;
    const float rstd = rsqrtf(var + 1e-5f);
    half8 o0, o1;
    #pragma unroll
    for (int j = 0; j < 8; ++j) {
        const int i0 = lane * 8 + j, i1 = 512 + lane * 8 + j;
        const float av = (f0[j] - mean) * rstd * gamma[i0] + beta[i0];
        const float bv = (f1[j] - mean) * rstd * gamma[i1] + beta[i1];
        o0[j] = (_Float16)(av > 0.f ? av : 0.f);
        o1[j] = (_Float16)(bv > 0.f ? bv : 0.f);
    }
    *(half8*)(ho + lane * 8) = o0;
    *(half8*)(ho + 512 + lane * 8) = o1;
}

// -----------------------------------------------------------------------------
extern "C" void kernel_launch(void* const* d_in, const int* in_sizes, int n_in,
                              void* d_out, int out_size, void* d_ws, size_t ws_size,
                              hipStream_t stream)
{
    (void)in_sizes; (void)n_in; (void)out_size;
    const size_t HH = (size_t)HDIM * HDIM;              // 262,144

    // ws layout (~113.8 MB; r9-r13 proved ws >= this)
    _Float16* wsH   = (_Float16*)d_ws;
    _Float16* slotB = wsH;                               // CH*1536
    _Float16* Xch   = slotB + (size_t)CH * 1536;         // CH*1536
    _Float16* Wouth = Xch   + (size_t)CH * 1536;         // 3*HH
    _Float16* Wg2h  = Wouth + 3 * HH;                    // 3*HH
    _Float16* WvT   = Wg2h  + 3 * HH;                    // 3*HH
    _Float16* WcoT  = WvT   + 3 * HH;                    // 3*HH
    _Float16* Wbig  = WcoT  + 3 * HH;                    // 4*HH (1024 x 1024)
    _Float16* Wc2   = Wbig  + 4 * HH;                    // 1*HH (512 x 512)
    _Float16* fc1h  = Wc2   + 1 * HH;                    // 6*HH
    _Float16* fc2h  = fc1h  + 6 * HH;                    // 2*HH
    float*    bco   = (float*)(fc2h + 2 * HH);           // 3*512
    float*    beff  = bco + 3 * 512;                     // 3*512
    _Float16* hws   = wsH;                               // h' after chunk loop
    const size_t need = (size_t)((char*)(beff + 3 * 512) - (char*)d_ws);
    if (ws_size < need) return;

    const float* X[3] = { (const float*)d_in[0], (const float*)d_in[1], (const float*)d_in[2] };
    const int asrc[3] = { 1, 0, 2 };

    // ---- weight prep (all tiny) ----
    CvtJobs cj;
    for (int m = 0; m < 3; ++m) {
        cj.j[m]     = { (const float*)d_in[5 + 4 * m], Wouth + m * HH, 128, 512, 128, 512 };
        cj.j[3 + m] = { (const float*)d_in[15 + 2 * m] + 512, Wg2h + m * HH, 256, 512, 128, 512 };
    }
    cj.j[6]  = { (const float*)d_in[15], Wbig,                    256, 1024, 128, 512 };
    cj.j[7]  = { (const float*)d_in[17], Wbig + 512 * 1024 + 512, 256, 1024, 128, 512 };
    cj.j[8]  = { (const float*)d_in[19], Wc2,                     256, 512,  128, 512 };
    cj.j[9]  = { (const float*)d_in[21], fc1h, 384, 1536, 384, 1024 };
    cj.j[10] = { (const float*)d_in[25], fc2h, 256, 1024, 256, 512 };
    cvt_rows<<<dim3(1024, 11, 1), 256, 0, stream>>>(cj);

    TcvtArgs ta;
    for (int m = 0; m < 3; ++m) ta.src[m] = (const float*)d_in[3 + 4 * m] + 2 * HH;
    ta.dst = WvT;
    tcvt512<<<dim3(16, 16, 3), 256, 0, stream>>>(ta);

    MvArgs mv;
    for (int m = 0; m < 3; ++m) {
        mv.W[m] = (const float*)d_in[5 + 4 * m];
        mv.x[m] = (const float*)d_in[4 + 4 * m] + 2 * HDIM;
        mv.b[m] = (const float*)d_in[6 + 4 * m];
    }
    mv.y = bco; mv.ldw = 512; mv.woff = 0;
    mv3<<<dim3(2, 3, 1), 256, 0, stream>>>(mv);

    GemmP p;
    p.bias = nullptr; p.coff = 0;
    p.zsA = p.zsW = p.zsC = 0;

    // WcoT_a = WvT_a @ Wout_a^T  (batched over z)
    p.A1 = WvT; p.ldA1 = 512;
    p.W = Wouth; p.ldw = 512;
    p.C = WcoT; p.ldc = 512;
    p.K = 512;
    p.zsA = (int)(HH * 2); p.zsW = (int)(HH * 2); p.zsC = (int)(HH * 2);
    gemm_k<0, 4><<<dim3(4, 4, 3), 256, 0, stream>>>(p);

    // Wbig off-diagonal blocks (z=2)
    p.A1 = Wg2h; p.zsA = (int)(HH * 2);
    p.W = WcoT + HH; p.zsW = -(int)(HH * 2);
    p.C = Wbig + 512; p.ldc = 1024; p.zsC = (int)((512 * 1024 - 512) * 2);
    gemm_k<0, 4><<<dim3(4, 4, 2), 256, 0, stream>>>(p);

    // Wc2 += Wg2_2 @ Wco_2
    p.A1 = Wg2h + 2 * HH; p.zsA = 0;
    p.W = WcoT + 2 * HH; p.zsW = 0;
    p.C = Wc2; p.ldc = 512; p.zsC = 0;
    gemm_k<2, 4><<<dim3(4, 4, 1), 256, 0, stream>>>(p);

    // beff
    for (int m = 0; m < 3; ++m) {
        mv.W[m] = (const float*)d_in[15 + 2 * m];
        mv.x[m] = bco + asrc[m] * 512;
        mv.b[m] = (const float*)d_in[16 + 2 * m];
    }
    mv.y = beff; mv.ldw = 1024; mv.woff = 512;
    mv3<<<dim3(2, 3, 1), 256, 0, stream>>>(mv);

    // ---- main pipeline, 2 M-chunks ----
    _Float16* hbuf = (_Float16*)d_out;
    Gemm8P g8;
    for (int c = 0; c < 2; ++c) {
        const size_t roff = (size_t)c * CH;

        cvt_chunk3<<<dim3(CH, 1, 1), 384, 0, stream>>>(
            X[0] + roff * HDIM, X[1] + roff * HDIM, X[2] + roff * HDIM, Xch);

        // gate01 (8-phase 256^2): slotB[:,0:1024] = Xc01 * sigma(Xc01 @ Wbig^T + beff)
        g8.A = Xch; g8.ldA = 1536;
        g8.W = Wbig; g8.ldW = 1024;
        g8.bias = beff;
        g8.C = slotB; g8.ldc = 1536; g8.coff = 0;
        g8.K = 1024;
        gemm8<1><<<dim3(CH / 256, 4, 1), 512, 0, stream>>>(g8);

        // gate2 (1-phase, proven): slotB[:,1024:1536]
        p.A1 = Xch + 1024; p.ldA1 = 1536;
        p.W = Wc2; p.ldw = 512;
        p.bias = beff + 1024;
        p.C = slotB; p.ldc = 1536; p.coff = 1024;
        p.K = 512; p.zsA = p.zsW = p.zsC = 0;
        gemm_k<1, 4><<<dim3(CH / BM, 4, 1), 256, 0, stream>>>(p);

        // fc1 (8-phase 256^2): h_chunk = allf @ fc1^T + fc1_b -> d_out fp16
        g8.A = slotB; g8.ldA = 1536;
        g8.W = fc1h; g8.ldW = 1536;
        g8.bias = (const float*)d_in[22];
        g8.C = hbuf + roff * 1024; g8.ldc = 1024; g8.coff = 0;
        g8.K = 1536;
        gemm8<0><<<dim3(CH / 256, 4, 1), 512, 0, stream>>>(g8);
    }

    // LayerNorm + ReLU: h (d_out) -> h' (ws)
    ln_relu<<<dim3(MROWS / 4, 1, 1), 256, 0, stream>>>(
        hbuf, hws, (const float*)d_in[23], (const float*)d_in[24]);

    // fc2 (1-phase EPI3): out = h' @ fc2^T + fc2_b -> d_out fp32
    p.A1 = hws; p.ldA1 = 1024;
    p.W = fc2h; p.ldw = 1024;
    p.bias = (const float*)d_in[26];
    p.C = d_out; p.ldc = HDIM; p.coff = 0;
    p.K = 1024; p.zsA = p.zsW = p.zsC = 0;
    gemm_k<3, 4><<<dim3(MROWS / BM, HDIM / BN, 1), 256, 0, stream>>>(p);
}

// Round 15
// 454.631 us; speedup vs baseline: 1.0254x; 1.0254x over previous
//
#include <hip/hip_runtime.h>
#include <stdint.h>
#include <stddef.h>

#define MROWS 32768
#define HDIM  512
#define CH    16384
#define BM 128
#define BN 128
#define BK 64

typedef __attribute__((ext_vector_type(8))) _Float16 half8;
typedef __attribute__((ext_vector_type(4))) _Float16 half4v;
typedef __attribute__((ext_vector_type(4))) float    f32x4;

// global -> LDS direct (16B/lane). LDS dest = wave-uniform base + lane*16.
static __device__ __forceinline__ void gld_lds16(const void* g, void* l) {
    __builtin_amdgcn_global_load_lds(
        (__attribute__((address_space(1))) void*)(uintptr_t)g,
        (__attribute__((address_space(3))) void*)(uint32_t)(uintptr_t)l,
        16, 0, 0);
}

// ---------------- fp32 -> fp16 row-structured conversion (weights) ------------
struct CvtJob  { const float* src; _Float16* dst; int srcld4, dstld, rowlen4, rows; };
struct CvtJobs { CvtJob j[11]; };

__global__ __launch_bounds__(256)
void cvt_rows(CvtJobs J) {
    const CvtJob jb = J.j[blockIdx.y];
    const int row = blockIdx.x;
    if (row >= jb.rows) return;
    const float4* __restrict__ s = (const float4*)jb.src + (size_t)row * jb.srcld4;
    _Float16* __restrict__ d = jb.dst + (size_t)row * jb.dstld;
    for (int c = threadIdx.x; c < jb.rowlen4; c += 256) {
        const float4 v = s[c];
        half4v o = { (_Float16)v.x, (_Float16)v.y, (_Float16)v.z, (_Float16)v.w };
        *(half4v*)(d + c * 4) = o;
    }
}

// ---------------- fp32 X chunk -> packed fp16 strip [X0|X1|X2] (ld 1536) ------
__global__ __launch_bounds__(384)
void cvt_chunk3(const float* __restrict__ x0, const float* __restrict__ x1,
                const float* __restrict__ x2, _Float16* __restrict__ dst) {
    const int row = blockIdx.x;
    const int mod = threadIdx.x >> 7;      // 0..2 (wave-uniform)
    const int c   = threadIdx.x & 127;     // float4 index within row
    const float* s = (mod == 0) ? x0 : (mod == 1) ? x1 : x2;
    const float4 v = ((const float4*)(s + (size_t)row * 512))[c];
    half4v o = { (_Float16)v.x, (_Float16)v.y, (_Float16)v.z, (_Float16)v.w };
    *(half4v*)(dst + (size_t)row * 1536 + mod * 512 + c * 4) = o;
}

// ---------------- fp32 -> fp16 transpose (512x512): dst[k][i] = src[i][k] -----
struct TcvtArgs { const float* src[3]; _Float16* dst; };
__global__ __launch_bounds__(256)
void tcvt512(TcvtArgs a) {
    __shared__ float t[32][33];
    const int m = blockIdx.z;
    const float* __restrict__ src = a.src[m];
    _Float16* __restrict__ dst = a.dst + (size_t)m * HDIM * HDIM;
    const int bx = blockIdx.x * 32, by = blockIdx.y * 32;
    const int tx = threadIdx.x & 31, ty = threadIdx.x >> 5;  // ty 0..7
    #pragma unroll
    for (int q = 0; q < 4; ++q)
        t[ty + q * 8][tx] = src[(size_t)(by + ty + q * 8) * 512 + bx + tx];
    __syncthreads();
    #pragma unroll
    for (int q = 0; q < 4; ++q)
        dst[(size_t)(bx + ty + q * 8) * 512 + by + tx] = (_Float16)t[tx][ty + q * 8];
}

// ---------------- small matvec ------------------------------------------------
struct MvArgs { const float* W[3]; const float* x[3]; const float* b[3]; float* y; int ldw, woff; };
__global__ __launch_bounds__(256)
void mv3(MvArgs a) {
    const int m = blockIdx.y;
    const int i = blockIdx.x * 256 + threadIdx.x;
    const float* __restrict__ W = a.W[m] + (size_t)i * a.ldw + a.woff;
    const float* __restrict__ x = a.x[m];
    float s = a.b[m][i];
    for (int j = 0; j < 512; ++j) s += W[j] * x[j];
    a.y[m * 512 + i] = s;
}

// ---------------- 1-phase GEMM (prep / gate2), proven r9-r14 ------------------
struct GemmP {
    const void* A1;
    const _Float16* W; const float* bias; void* C;
    int K, ldA1, ldw, ldc, coff;
    int zsA, zsW, zsC;
};

template<int EPI, int OCC>
__global__ __launch_bounds__(256, OCC)
void gemm_k(GemmP p) {
    __shared__ __align__(16) unsigned char smem[32768];
    _Float16* Asm = (_Float16*)smem;
    _Float16* Bsm = (_Float16*)(smem + 16384);

    const int tid  = threadIdx.x;
    const int wid  = tid >> 6;
    const int lane = tid & 63;
    const int m0 = blockIdx.x * BM;
    const int n0 = blockIdx.y * BN;
    const ptrdiff_t zz = (ptrdiff_t)blockIdx.z;
    const _Float16* __restrict__ A1h = (const _Float16*)((const char*)p.A1 + zz * p.zsA);
    const _Float16* __restrict__ Wp  = (const _Float16*)((const char*)p.W + zz * p.zsW);
    char* Cz = (char*)p.C + zz * p.zsC;

    const int wr = (wid >> 1) * 64;
    const int wc = (wid & 1) * 64;
    const int l15 = lane & 15;
    const int lhi = lane >> 4;

    f32x4 acc[4][4] = {};

    for (int kt = 0; kt < p.K; kt += BK) {
        #pragma unroll
        for (int i = 0; i < 4; ++i) {
            const int seg = wid * 256 + i * 64 + lane;
            const int row = seg >> 3;
            const int ke  = (seg & 7) * 8;
            gld_lds16(Wp  + (size_t)(n0 + row) * p.ldw  + kt + ke, &Bsm[seg * 8]);
            gld_lds16(A1h + (size_t)(m0 + row) * p.ldA1 + kt + ke, &Asm[seg * 8]);
        }
        __syncthreads();
        #pragma unroll
        for (int kk = 0; kk < BK; kk += 32) {
            half8 fa[4], fb[4];
            #pragma unroll
            for (int i = 0; i < 4; ++i) {
                fa[i] = *(const half8*)&Asm[(wr + i * 16 + l15) * BK + kk + lhi * 8];
                fb[i] = *(const half8*)&Bsm[(wc + i * 16 + l15) * BK + kk + lhi * 8];
            }
            #pragma unroll
            for (int i = 0; i < 4; ++i)
                #pragma unroll
                for (int j = 0; j < 4; ++j)
                    acc[i][j] = __builtin_amdgcn_mfma_f32_16x16x32_f16(fa[i], fb[j], acc[i][j], 0, 0, 0);
        }
        __syncthreads();
    }

    if (EPI == 3) {
        float* Cf = (float*)smem;
        float* __restrict__ C = (float*)Cz;
        #pragma unroll
        for (int h = 0; h < 2; ++h) {
            if ((wr >> 6) == h) {
                #pragma unroll
                for (int j = 0; j < 4; ++j) {
                    const int col = wc + j * 16 + l15;
                    const float bia = p.bias ? p.bias[n0 + col] : 0.f;
                    #pragma unroll
                    for (int i = 0; i < 4; ++i)
                        #pragma unroll
                        for (int r = 0; r < 4; ++r)
                            Cf[(i * 16 + lhi * 4 + r) * 128 + col] = acc[i][j][r] + bia;
                }
            }
            __syncthreads();
            #pragma unroll
            for (int pph = 0; pph < 8; ++pph) {
                const int seg = pph * 256 + tid;
                const int row = seg >> 5, cs = seg & 31;
                const float4 v = *(const float4*)&Cf[row * 128 + cs * 4];
                *(float4*)&C[(size_t)(m0 + h * 64 + row) * p.ldc + n0 + cs * 4] = v;
            }
            __syncthreads();
        }
    } else {
        _Float16* Ct = (_Float16*)smem;
        #pragma unroll
        for (int j = 0; j < 4; ++j) {
            const int col = wc + j * 16 + l15;
            const float bia = (EPI == 2) ? 0.f : (p.bias ? p.bias[n0 + col] : 0.f);
            #pragma unroll
            for (int i = 0; i < 4; ++i)
                #pragma unroll
                for (int r = 0; r < 4; ++r) {
                    float v = acc[i][j][r] + bia;
                    if (EPI == 1) v = 1.f / (1.f + __expf(-v));
                    Ct[(wr + i * 16 + lhi * 4 + r) * 128 + col] = (_Float16)v;
                }
        }
        __syncthreads();
        _Float16* __restrict__ C = (_Float16*)Cz;
        #pragma unroll
        for (int pph = 0; pph < 8; ++pph) {
            const int seg = pph * 256 + tid;
            const int row = seg >> 4, cs = seg & 15;
            half8 hv = *(const half8*)&Ct[row * 128 + cs * 8];
            const size_t cidx = (size_t)(m0 + row) * p.ldc + p.coff + n0 + cs * 8;
            if (EPI == 1) {
                const half8 xv = *(const half8*)(A1h + (size_t)(m0 + row) * p.ldA1
                                                 + n0 + cs * 8);
                hv = hv * xv;
            }
            if (EPI == 2) { const half8 old = *(const half8*)&C[cidx]; hv = hv + old; }
            *(half8*)&C[cidx] = hv;
        }
    }
}

// ---------------- 2-phase/tile 256x256 GEMM, counted vmcnt (T2+T3+T4+T5) -----
// 512 thr = 8 waves (2M x 4N); per-wave out 128x64.
// LDS: per operand [2 buf][2 kh][256 rows][4 x 16B] (kh = 32 K-cols, 16KB rgn).
// Per tile t (buffer q=t&1), 2 phases (kh=0,1). Each phase:
//   12 ds_read (fa[8] + fb[4]) ; stage (kh0-phase: kh1(t+1); kh1-phase:
//   kh0(t+2)) ; lgkmcnt(0) ; 32 MFMA ; counted vmcnt ; s_barrier.
// 32 MFMA per barrier (AITER density), half the barriers of r14.
// Wait ledger (4 loads/thread per STAGE8):
//   end kh0(t): drain kh1(t)  -> vmcnt(8) if t+1<nT else vmcnt(0)
//   end kh1(t): drain kh0(t+1)-> vmcnt(8) if t+2<nT else vmcnt(4) if t+1<nT
// Region safety: stage targets never alias live reads (kh1(t+1) -> buf q^1;
// kh0(t+2) -> region whose reads completed at the preceding barrier).
// MFMA order per acc element identical to r13/r14 -> bit-identical output.
// Swizzle (both-sides, rule #21): read slot = lhi ^ ((row>>1)&3); source col
// kc = i ^ ((row>>1)&3).
struct Gemm8P {
    const _Float16* A; const _Float16* W; const float* bias; void* C;
    int K, ldA, ldW, ldc, coff;
};

template<int EPI>
__global__ __launch_bounds__(512, 1)
void gemm8(Gemm8P p) {
    __shared__ __align__(16) unsigned char lds[131072];
    char* LA = (char*)lds;             // A regions: (q*2+kh)*16KB
    char* LB = (char*)lds + 65536;

    const int tid  = threadIdx.x;
    const int wid  = tid >> 6;
    const int lane = tid & 63;
    const int wm = wid >> 2;           // 0..1
    const int wn = wid & 3;            // 0..3
    const int l15 = lane & 15;
    const int lhi = lane >> 4;
    const int m0 = blockIdx.x * 256;
    const int n0 = blockIdx.y * 256;
    const _Float16* __restrict__ A = p.A;
    const _Float16* __restrict__ W = p.W;
    const int ldA = p.ldA, ldW = p.ldW;
    const int nT = p.K >> 6;

    f32x4 acc[8][4] = {};

    auto stageh = [&](const _Float16* src, int ld, int r0, char* base, int t, int kh) {
        const int q = t & 1;
        const int kt = t * 64 + kh * 32;
        char* dst = base + (size_t)(q * 2 + kh) * 16384;
        #pragma unroll
        for (int k = 0; k < 2; ++k) {
            const int j = tid + k * 512;          // 0..1023
            const int row = j >> 2, i = j & 3;
            const int kc = i ^ ((row >> 1) & 3);  // pre-swizzled source col
            gld_lds16(src + (size_t)(r0 + row) * ld + kt + kc * 8,
                      dst + (size_t)j * 16);
        }
    };
    #define STAGE8(t, kh) { stageh(A, ldA, m0, LA, (t), (kh)); stageh(W, ldW, n0, LB, (t), (kh)); }

    // prologue: kh0(0), kh1(0), kh0(1) -> ages mimic steady state
    STAGE8(0, 0);
    STAGE8(0, 1);
    if (nT > 1) { STAGE8(1, 0); asm volatile("s_waitcnt vmcnt(8)" ::: "memory"); }
    else        {               asm volatile("s_waitcnt vmcnt(0)" ::: "memory"); }
    __builtin_amdgcn_s_barrier();
    asm volatile("" ::: "memory");

    for (int t = 0; t < nT; ++t) {
        const int q = t & 1;
        #pragma unroll
        for (int kh = 0; kh < 2; ++kh) {
            const char* ra = LA + (size_t)(q * 2 + kh) * 16384;
            const char* rb = LB + (size_t)(q * 2 + kh) * 16384;
            half8 fa[8], fb[4];
            #pragma unroll
            for (int nf = 0; nf < 4; ++nf) {
                const int row = wn * 64 + nf * 16 + l15;
                const int sl = lhi ^ ((row >> 1) & 3);
                fb[nf] = *(const half8*)(rb + ((size_t)row * 4 + sl) * 16);
            }
            #pragma unroll
            for (int mf = 0; mf < 8; ++mf) {
                const int row = wm * 128 + mf * 16 + l15;
                const int sl = lhi ^ ((row >> 1) & 3);
                fa[mf] = *(const half8*)(ra + ((size_t)row * 4 + sl) * 16);
            }
            if (kh == 0 && t + 1 < nT) STAGE8(t + 1, 1);
            if (kh == 1 && t + 2 < nT) STAGE8(t + 2, 0);
            asm volatile("s_waitcnt lgkmcnt(0)" ::: "memory");
            __builtin_amdgcn_sched_barrier(0);
            __builtin_amdgcn_s_setprio(1);
            #pragma unroll
            for (int mf = 0; mf < 8; ++mf)
                #pragma unroll
                for (int nf = 0; nf < 4; ++nf)
                    acc[mf][nf] = __builtin_amdgcn_mfma_f32_16x16x32_f16(
                        fa[mf], fb[nf], acc[mf][nf], 0, 0, 0);
            __builtin_amdgcn_s_setprio(0);
            if (kh == 0) {
                if (t + 1 < nT) asm volatile("s_waitcnt vmcnt(8)" ::: "memory");
                else            asm volatile("s_waitcnt vmcnt(0)" ::: "memory");
            } else {
                if (t + 2 < nT)      asm volatile("s_waitcnt vmcnt(8)" ::: "memory");
                else if (t + 1 < nT) asm volatile("s_waitcnt vmcnt(4)" ::: "memory");
            }
            asm volatile("" ::: "memory");
            __builtin_amdgcn_s_barrier();
            asm volatile("" ::: "memory");
        }
    }

    if (EPI == 3) {
        // fp32 epilogue in two 128-row half-passes (128 x 256 fp32 = 128KB)
        float* Cf = (float*)lds;
        float* __restrict__ C = (float*)p.C;
        #pragma unroll
        for (int h = 0; h < 2; ++h) {
            if (wm == h) {
                #pragma unroll
                for (int mf = 0; mf < 8; ++mf)
                    #pragma unroll
                    for (int nf = 0; nf < 4; ++nf) {
                        const int col = wn * 64 + nf * 16 + l15;
                        const float bia = p.bias[n0 + col];
                        #pragma unroll
                        for (int r = 0; r < 4; ++r)
                            Cf[(mf * 16 + lhi * 4 + r) * 256 + col] = acc[mf][nf][r] + bia;
                    }
            }
            __syncthreads();
            #pragma unroll
            for (int it = 0; it < 16; ++it) {
                const int u = it * 512 + tid;       // 8192 float4 units
                const int row = u >> 6, cs = u & 63;
                const float4 v = *(const float4*)&Cf[row * 256 + cs * 4];
                *(float4*)&C[(size_t)(m0 + h * 128 + row) * p.ldc + n0 + cs * 4] = v;
            }
            __syncthreads();
        }
    } else {
        // fp16 epilogue: fragments -> LDS (256x256 fp16 = 128KB) -> stores
        _Float16* Ct = (_Float16*)lds;
        _Float16* __restrict__ C = (_Float16*)p.C;
        #pragma unroll
        for (int mf = 0; mf < 8; ++mf)
            #pragma unroll
            for (int nf = 0; nf < 4; ++nf) {
                const int col = wn * 64 + nf * 16 + l15;
                const float bia = p.bias[n0 + col];
                #pragma unroll
                for (int r = 0; r < 4; ++r) {
                    float v = acc[mf][nf][r] + bia;
                    if (EPI == 1) v = 1.f / (1.f + __expf(-v));   // sigma
                    Ct[(wm * 128 + mf * 16 + lhi * 4 + r) * 256 + col] = (_Float16)v;
                }
            }
        __syncthreads();
        #pragma unroll
        for (int it = 0; it < 16; ++it) {
            const int u = it * 512 + tid;          // 8192 x 16B units
            const int row = u >> 5, cs = u & 31;
            half8 hv = *(const half8*)&Ct[row * 256 + cs * 8];
            if (EPI == 1) {
                const half8 xv = *(const half8*)(A + (size_t)(m0 + row) * ldA + n0 + cs * 8);
                hv = hv * xv;                       // x * sigmoid
            }
            *(half8*)&C[(size_t)(m0 + row) * p.ldc + p.coff + n0 + cs * 8] = hv;
        }
    }
}

// ---------------- LayerNorm(1024) + ReLU: d_out(h fp16) -> ws(h' fp16) --------
__global__ __launch_bounds__(256)
void ln_relu(const _Float16* __restrict__ hin, _Float16* __restrict__ hout,
             const float* __restrict__ gamma, const float* __restrict__ beta) {
    const int row  = blockIdx.x * 4 + (threadIdx.x >> 6);
    const int lane = threadIdx.x & 63;
    const _Float16* hr = hin + (size_t)row * 1024;
    _Float16* ho = hout + (size_t)row * 1024;
    const half8 v0 = *(const half8*)(hr + lane * 8);
    const half8 v1 = *(const half8*)(hr + 512 + lane * 8);
    float f0[8], f1[8];
    float s = 0.f, s2 = 0.f;
    #pragma unroll
    for (int j = 0; j < 8; ++j) {
        f0[j] = (float)v0[j]; s += f0[j]; s2 += f0[j] * f0[j];
        f1[j] = (float)v1[j]; s += f1[j]; s2 += f1[j] * f1[j];
    }
    #pragma unroll
    for (int off = 32; off > 0; off >>= 1) {
        s  += __shfl_xor(s,  off, 64);
        s2 += __shfl_xor(s2, off, 64);
    }
    const float mean = s * (1.f / 1024.f);
    const float var  = s2 * (1.f / 1024.f) - mean * mean;
    const float rstd = rsqrtf(var + 1e-5f);
    half8 o0, o1;
    #pragma unroll
    for (int j = 0; j < 8; ++j) {
        const int i0 = lane * 8 + j, i1 = 512 + lane * 8 + j;
        const float av = (f0[j] - mean) * rstd * gamma[i0] + beta[i0];
        const float bv = (f1[j] - mean) * rstd * gamma[i1] + beta[i1];
        o0[j] = (_Float16)(av > 0.f ? av : 0.f);
        o1[j] = (_Float16)(bv > 0.f ? bv : 0.f);
    }
    *(half8*)(ho + lane * 8) = o0;
    *(half8*)(ho + 512 + lane * 8) = o1;
}

// -----------------------------------------------------------------------------
extern "C" void kernel_launch(void* const* d_in, const int* in_sizes, int n_in,
                              void* d_out, int out_size, void* d_ws, size_t ws_size,
                              hipStream_t stream)
{
    (void)in_sizes; (void)n_in; (void)out_size;
    const size_t HH = (size_t)HDIM * HDIM;              // 262,144

    // ws layout (~113.8 MB; r9-r14 proved ws >= this)
    _Float16* wsH   = (_Float16*)d_ws;
    _Float16* slotB = wsH;                               // CH*1536
    _Float16* Xch   = slotB + (size_t)CH * 1536;         // CH*1536
    _Float16* Wouth = Xch   + (size_t)CH * 1536;         // 3*HH
    _Float16* Wg2h  = Wouth + 3 * HH;                    // 3*HH
    _Float16* WvT   = Wg2h  + 3 * HH;                    // 3*HH
    _Float16* WcoT  = WvT   + 3 * HH;                    // 3*HH
    _Float16* Wbig  = WcoT  + 3 * HH;                    // 4*HH (1024 x 1024)
    _Float16* Wc2   = Wbig  + 4 * HH;                    // 1*HH (512 x 512)
    _Float16* fc1h  = Wc2   + 1 * HH;                    // 6*HH
    _Float16* fc2h  = fc1h  + 6 * HH;                    // 2*HH
    float*    bco   = (float*)(fc2h + 2 * HH);           // 3*512
    float*    beff  = bco + 3 * 512;                     // 3*512
    _Float16* hws   = wsH;                               // h' after chunk loop
    const size_t need = (size_t)((char*)(beff + 3 * 512) - (char*)d_ws);
    if (ws_size < need) return;

    const float* X[3] = { (const float*)d_in[0], (const float*)d_in[1], (const float*)d_in[2] };
    const int asrc[3] = { 1, 0, 2 };

    // ---- weight prep (all tiny) ----
    CvtJobs cj;
    for (int m = 0; m < 3; ++m) {
        cj.j[m]     = { (const float*)d_in[5 + 4 * m], Wouth + m * HH, 128, 512, 128, 512 };
        cj.j[3 + m] = { (const float*)d_in[15 + 2 * m] + 512, Wg2h + m * HH, 256, 512, 128, 512 };
    }
    cj.j[6]  = { (const float*)d_in[15], Wbig,                    256, 1024, 128, 512 };
    cj.j[7]  = { (const float*)d_in[17], Wbig + 512 * 1024 + 512, 256, 1024, 128, 512 };
    cj.j[8]  = { (const float*)d_in[19], Wc2,                     256, 512,  128, 512 };
    cj.j[9]  = { (const float*)d_in[21], fc1h, 384, 1536, 384, 1024 };
    cj.j[10] = { (const float*)d_in[25], fc2h, 256, 1024, 256, 512 };
    cvt_rows<<<dim3(1024, 11, 1), 256, 0, stream>>>(cj);

    TcvtArgs ta;
    for (int m = 0; m < 3; ++m) ta.src[m] = (const float*)d_in[3 + 4 * m] + 2 * HH;
    ta.dst = WvT;
    tcvt512<<<dim3(16, 16, 3), 256, 0, stream>>>(ta);

    MvArgs mv;
    for (int m = 0; m < 3; ++m) {
        mv.W[m] = (const float*)d_in[5 + 4 * m];
        mv.x[m] = (const float*)d_in[4 + 4 * m] + 2 * HDIM;
        mv.b[m] = (const float*)d_in[6 + 4 * m];
    }
    mv.y = bco; mv.ldw = 512; mv.woff = 0;
    mv3<<<dim3(2, 3, 1), 256, 0, stream>>>(mv);

    GemmP p;
    p.bias = nullptr; p.coff = 0;
    p.zsA = p.zsW = p.zsC = 0;

    // WcoT_a = WvT_a @ Wout_a^T  (batched over z)
    p.A1 = WvT; p.ldA1 = 512;
    p.W = Wouth; p.ldw = 512;
    p.C = WcoT; p.ldc = 512;
    p.K = 512;
    p.zsA = (int)(HH * 2); p.zsW = (int)(HH * 2); p.zsC = (int)(HH * 2);
    gemm_k<0, 4><<<dim3(4, 4, 3), 256, 0, stream>>>(p);

    // Wbig off-diagonal blocks (z=2)
    p.A1 = Wg2h; p.zsA = (int)(HH * 2);
    p.W = WcoT + HH; p.zsW = -(int)(HH * 2);
    p.C = Wbig + 512; p.ldc = 1024; p.zsC = (int)((512 * 1024 - 512) * 2);
    gemm_k<0, 4><<<dim3(4, 4, 2), 256, 0, stream>>>(p);

    // Wc2 += Wg2_2 @ Wco_2
    p.A1 = Wg2h + 2 * HH; p.zsA = 0;
    p.W = WcoT + 2 * HH; p.zsW = 0;
    p.C = Wc2; p.ldc = 512; p.zsC = 0;
    gemm_k<2, 4><<<dim3(4, 4, 1), 256, 0, stream>>>(p);

    // beff
    for (int m = 0; m < 3; ++m) {
        mv.W[m] = (const float*)d_in[15 + 2 * m];
        mv.x[m] = bco + asrc[m] * 512;
        mv.b[m] = (const float*)d_in[16 + 2 * m];
    }
    mv.y = beff; mv.ldw = 1024; mv.woff = 512;
    mv3<<<dim3(2, 3, 1), 256, 0, stream>>>(mv);

    // ---- main pipeline, 2 M-chunks ----
    _Float16* hbuf = (_Float16*)d_out;
    Gemm8P g8;
    for (int c = 0; c < 2; ++c) {
        const size_t roff = (size_t)c * CH;

        cvt_chunk3<<<dim3(CH, 1, 1), 384, 0, stream>>>(
            X[0] + roff * HDIM, X[1] + roff * HDIM, X[2] + roff * HDIM, Xch);

        // gate01 (gemm8): slotB[:,0:1024] = Xc01 * sigma(Xc01 @ Wbig^T + beff)
        g8.A = Xch; g8.ldA = 1536;
        g8.W = Wbig; g8.ldW = 1024;
        g8.bias = beff;
        g8.C = slotB; g8.ldc = 1536; g8.coff = 0;
        g8.K = 1024;
        gemm8<1><<<dim3(CH / 256, 4, 1), 512, 0, stream>>>(g8);

        // gate2 (1-phase, proven): slotB[:,1024:1536]
        p.A1 = Xch + 1024; p.ldA1 = 1536;
        p.W = Wc2; p.ldw = 512;
        p.bias = beff + 1024;
        p.C = slotB; p.ldc = 1536; p.coff = 1024;
        p.K = 512; p.zsA = p.zsW = p.zsC = 0;
        gemm_k<1, 4><<<dim3(CH / BM, 4, 1), 256, 0, stream>>>(p);

        // fc1 (gemm8): h_chunk = allf @ fc1^T + fc1_b -> d_out fp16
        g8.A = slotB; g8.ldA = 1536;
        g8.W = fc1h; g8.ldW = 1536;
        g8.bias = (const float*)d_in[22];
        g8.C = hbuf + roff * 1024; g8.ldc = 1024; g8.coff = 0;
        g8.K = 1536;
        gemm8<0><<<dim3(CH / 256, 4, 1), 512, 0, stream>>>(g8);
    }

    // LayerNorm + ReLU: h (d_out) -> h' (ws)
    ln_relu<<<dim3(MROWS / 4, 1, 1), 256, 0, stream>>>(
        hbuf, hws, (const float*)d_in[23], (const float*)d_in[24]);

    // fc2 (gemm8 EPI3): out = h' @ fc2^T + fc2_b -> d_out fp32
    g8.A = hws; g8.ldA = 1024;
    g8.W = fc2h; g8.ldW = 1024;
    g8.bias = (const float*)d_in[26];
    g8.C = d_out; g8.ldc = HDIM; g8.coff = 0;
    g8.K = 1024;
    gemm8<3><<<dim3(MROWS / 256, HDIM / 256, 1), 512, 0, stream>>>(g8);
}